// Round 1
// 480.467 us; speedup vs baseline: 1.1369x; 1.1369x over previous
//
#include <hip/hip_runtime.h>
#include <hip/hip_bf16.h>

#define H 512
#define B 64
#define S 2048

typedef __bf16 bf16x8 __attribute__((ext_vector_type(8)));
typedef float f32x4 __attribute__((ext_vector_type(4)));

// pack two fp32 -> two bf16 (RNE) in one uint (low = x)
__device__ __forceinline__ unsigned cvt2(float x, float y) {
    union { __hip_bfloat162 h; unsigned u; } cv;
    cv.h = __float22bfloat162_rn(make_float2(x, y));
    return cv.u;
}

__device__ __forceinline__ float fast_tanh(float x) {
    float e = __expf(2.0f * x);
    float r = __builtin_amdgcn_rcpf(e + 1.0f);
    return 1.0f - 2.0f * r;
}

// async 16B global -> LDS (wave-uniform LDS base + lane*16; global addr per-lane)
__device__ __forceinline__ void gload_lds16(const void* g, void* l) {
    __builtin_amdgcn_global_load_lds(
        (const __attribute__((address_space(1))) unsigned int*)g,
        (__attribute__((address_space(3))) unsigned int*)l, 16, 0, 0);
}

// W_w fp32 -> bf16 once (removes the per-K-step repack from the hot loop)
__global__ __launch_bounds__(256) void w16_kernel(const float* __restrict__ Ww,
                                                  unsigned short* __restrict__ w16) {
    const int i = (blockIdx.x * 256 + threadIdx.x) * 8;
    float4 a = *(const float4*)(Ww + i);
    float4 b = *(const float4*)(Ww + i + 4);
    uint4 p;
    p.x = cvt2(a.x, a.y); p.y = cvt2(a.z, a.w);
    p.z = cvt2(b.x, b.y); p.w = cvt2(b.z, b.w);
    *(uint4*)(w16 + i) = p;
}

// u[b,k] = U_b[k] + W_b[k] + sum_h U_w[k,h] * hid[b,h]
__global__ __launch_bounds__(256) void u_kernel(
        const float* __restrict__ hid, const float* __restrict__ Uw,
        const float* __restrict__ Ub, const float* __restrict__ Wb,
        float* __restrict__ u) {
    const int b = blockIdx.y;
    const int k = blockIdx.x * 4 + (threadIdx.x >> 6);
    const int lane = threadIdx.x & 63;
    const float4* wrow = (const float4*)(Uw + (size_t)k * H);
    const float4* hrow = (const float4*)(hid + (size_t)b * H);
    float4 w0 = wrow[lane * 2], w1 = wrow[lane * 2 + 1];
    float4 h0 = hrow[lane * 2], h1 = hrow[lane * 2 + 1];
    float acc = w0.x * h0.x + w0.y * h0.y + w0.z * h0.z + w0.w * h0.w
              + w1.x * h1.x + w1.y * h1.y + w1.z * h1.z + w1.w * h1.w;
    #pragma unroll
    for (int off = 1; off < 64; off <<= 1) acc += __shfl_xor(acc, off, 64);
    if (lane == 0) u[b * H + k] = acc + Ub[k] + Wb[k];
}

// ---------------------------------------------------------------------------
// energy: enc -> A-fragment REGISTERS once (32 rows/wave x full H, bf16),
// W16 streamed through double-buffered LDS chunks (32 cols x 512 h = 32 KB)
// via global_load_lds with counted vmcnt(8). XOR-swizzle (col&7)<<4 applied
// on the pre-swizzled global SOURCE (LDS dest linear) + on ds_read addr.
// ---------------------------------------------------------------------------
#define CN  32
#define NCH 16               // H / CN
#define CHB (CN * H * 2)     // 32768 bytes per chunk

__global__ __launch_bounds__(256, 2) void energy_kernel(
        const float* __restrict__ enc, const unsigned short* __restrict__ w16,
        const float* __restrict__ Vw, const float* __restrict__ u,
        float* __restrict__ energy) {
    const int s0  = blockIdx.x * 128;
    const int b   = blockIdx.y;
    const int tid = threadIdx.x;
    const int wave = tid >> 6, lane = tid & 63;
    const int quad = lane >> 4, c = lane & 15;

    __shared__ unsigned char Bs[2][CHB];      // 64 KB double buffer
    __shared__ float uS[H], vS[H];            // 4 KB

    // stage W chunk 0 (issued first -> oldest in vmcnt FIFO)
    #pragma unroll
    for (int i = 0; i < 8; ++i) {
        const int row = i * 4 + wave;                 // wave-uniform LDS row
        const int d   = (row << 10) + lane * 16;
        gload_lds16((const unsigned char*)w16 + (d ^ ((row & 7) << 4)),
                    &Bs[0][row << 10]);
    }

    for (int i = tid; i < H; i += 256) { uS[i] = u[b * H + i]; vS[i] = Vw[i]; }

    // A panel -> registers: lane holds rows (g-group + c), h = t*32 + quad*8 .. +7
    bf16x8 areg[2][16];
    #pragma unroll
    for (int g = 0; g < 2; ++g) {
        const float* pa = enc + ((size_t)(b * S + s0 + wave * 32 + g * 16 + c)) * H + quad * 8;
        float4 x0[16], x1[16];
        #pragma unroll
        for (int t = 0; t < 16; ++t) {
            x0[t] = *(const float4*)(pa + t * 32);
            x1[t] = *(const float4*)(pa + t * 32 + 4);
        }
        #pragma unroll
        for (int t = 0; t < 16; ++t) {
            uint4 p;
            p.x = cvt2(x0[t].x, x0[t].y); p.y = cvt2(x0[t].z, x0[t].w);
            p.z = cvt2(x1[t].x, x1[t].y); p.w = cvt2(x1[t].z, x1[t].w);
            areg[g][t] = *(bf16x8*)&p;
        }
        __builtin_amdgcn_sched_barrier(0);   // cap prologue register pressure
    }

    float esum[2][4] = {};
    const int mask = (c & 7) << 4;

    #pragma unroll 2
    for (int cc = 0; cc < NCH; ++cc) {
        const int buf = cc & 1;
        if (cc) __syncthreads();             // all waves done reading buf^1
        if (cc < NCH - 1) {                  // prefetch chunk cc+1
            const unsigned char* src = (const unsigned char*)w16 + (cc + 1) * CHB;
            #pragma unroll
            for (int i = 0; i < 8; ++i) {
                const int row = i * 4 + wave;
                const int d   = (row << 10) + lane * 16;
                gload_lds16(src + (d ^ ((row & 7) << 4)), &Bs[buf ^ 1][row << 10]);
            }
            asm volatile("s_waitcnt vmcnt(8)" ::: "memory");  // chunk cc done, cc+1 in flight
        } else {
            asm volatile("s_waitcnt vmcnt(0)" ::: "memory");
        }
        __syncthreads();

        const unsigned char* bb = Bs[buf];
        f32x4 acc[2][2] = {};
        #pragma unroll
        for (int t = 0; t < 16; ++t) {
            const int base = t * 64 + quad * 16;
            bf16x8 b0 = *(const bf16x8*)(bb + ((( c       << 10) + base) ^ mask));
            bf16x8 b1 = *(const bf16x8*)(bb + ((((16 + c) << 10) + base) ^ mask));
            acc[0][0] = __builtin_amdgcn_mfma_f32_16x16x32_bf16(areg[0][t], b0, acc[0][0], 0, 0, 0);
            acc[1][0] = __builtin_amdgcn_mfma_f32_16x16x32_bf16(areg[1][t], b0, acc[1][0], 0, 0, 0);
            acc[0][1] = __builtin_amdgcn_mfma_f32_16x16x32_bf16(areg[0][t], b1, acc[0][1], 0, 0, 0);
            acc[1][1] = __builtin_amdgcn_mfma_f32_16x16x32_bf16(areg[1][t], b1, acc[1][1], 0, 0, 0);
        }
        // fold chunk into energies: esum[g][r] += v[col]*tanh(u[col]+C)
        #pragma unroll
        for (int ct = 0; ct < 2; ++ct) {
            const int col = cc * CN + ct * 16 + c;
            const float vv = vS[col], uu = uS[col];
            #pragma unroll
            for (int g = 0; g < 2; ++g)
                #pragma unroll
                for (int r = 0; r < 4; ++r)
                    esum[g][r] += vv * fast_tanh(uu + acc[g][ct][r]);
        }
    }

    // reduce over the 16 col-lanes; each wave owns its rows -> direct store
    #pragma unroll
    for (int g = 0; g < 2; ++g)
        #pragma unroll
        for (int r = 0; r < 4; ++r) {
            float e = esum[g][r];
            e += __shfl_xor(e, 1, 64);
            e += __shfl_xor(e, 2, 64);
            e += __shfl_xor(e, 4, 64);
            e += __shfl_xor(e, 8, 64);
            if (c == 0)
                energy[b * S + s0 + wave * 32 + g * 16 + quad * 4 + r] = e;
        }
}

__global__ void softmax_kernel(const float* __restrict__ energy, float* __restrict__ attn) {
    int b = blockIdx.x;
    int t = threadIdx.x;              // 256
    const float* e = energy + b * S;
    float v[8];
    float m = -1e30f;
    #pragma unroll
    for (int i = 0; i < 8; ++i) { v[i] = e[t + i * 256]; m = fmaxf(m, v[i]); }
    #pragma unroll
    for (int off = 1; off < 64; off <<= 1) m = fmaxf(m, __shfl_xor(m, off, 64));
    __shared__ float redm[4], reds[4];
    if ((t & 63) == 0) redm[t >> 6] = m;
    __syncthreads();
    m = fmaxf(fmaxf(redm[0], redm[1]), fmaxf(redm[2], redm[3]));
    float s = 0.f;
    #pragma unroll
    for (int i = 0; i < 8; ++i) { v[i] = __expf(v[i] - m); s += v[i]; }
    #pragma unroll
    for (int off = 1; off < 64; off <<= 1) s += __shfl_xor(s, off, 64);
    if ((t & 63) == 0) reds[t >> 6] = s;
    __syncthreads();
    float inv = 1.0f / (reds[0] + reds[1] + reds[2] + reds[3]);
    #pragma unroll
    for (int i = 0; i < 8; ++i) attn[b * S + t + i * 256] = v[i] * inv;
}

#define CCHUNK 128
__global__ __launch_bounds__(256) void context_kernel(
        const float* __restrict__ enc, const float* __restrict__ attn,
        float* __restrict__ ctx) {
    int b  = blockIdx.x >> 4;
    int ch = blockIdx.x & 15;
    int t  = threadIdx.x;             // 256
    __shared__ float aS[CCHUNK];
    if (t < CCHUNK) aS[t] = attn[b * S + ch * CCHUNK + t];
    __syncthreads();
    const float* ebase = enc + ((size_t)(b * S + ch * CCHUNK)) * H + t;
    float c0 = 0.f, c1 = 0.f;
    #pragma unroll 8
    for (int s = 0; s < CCHUNK; ++s) {
        float a = aS[s];
        c0 += a * ebase[(size_t)s * H];
        c1 += a * ebase[(size_t)s * H + 256];
    }
    atomicAdd(&ctx[b * H + t], c0);
    atomicAdd(&ctx[b * H + t + 256], c1);
}

extern "C" void kernel_launch(void* const* d_in, const int* in_sizes, int n_in,
                              void* d_out, int out_size, void* d_ws, size_t ws_size,
                              hipStream_t stream) {
    (void)in_sizes; (void)n_in; (void)out_size; (void)ws_size;
    const float* hid = (const float*)d_in[0];
    const float* enc = (const float*)d_in[1];
    const float* Uw  = (const float*)d_in[2];
    const float* Ub  = (const float*)d_in[3];
    const float* Ww  = (const float*)d_in[4];
    const float* Wb  = (const float*)d_in[5];
    const float* Vw  = (const float*)d_in[6];
    // V_b unused: softmax shift-invariant, energy not an output.

    float* out_ctx  = (float*)d_out;          // 64*512
    float* out_attn = out_ctx + B * H;        // 64*2048
    float* energy   = (float*)d_ws;           // 64*2048 fp32
    float* u        = energy + B * S;         // 64*512 fp32
    unsigned short* w16 = (unsigned short*)(u + B * H);   // 512*512 bf16

    hipMemsetAsync(d_out, 0, (size_t)B * H * sizeof(float), stream);   // ctx accum target

    w16_kernel<<<dim3(H * H / (256 * 8)), 256, 0, stream>>>(Ww, w16);
    u_kernel<<<dim3(H / 4, B), 256, 0, stream>>>(hid, Uw, Ub, Wb, u);
    energy_kernel<<<dim3(S / 128, B), 256, 0, stream>>>(enc, w16, Vw, u, energy);
    softmax_kernel<<<B, 256, 0, stream>>>(energy, out_attn);
    context_kernel<<<B * (S / CCHUNK), 256, 0, stream>>>(enc, out_attn, out_ctx);
}

// Round 2
// 479.798 us; speedup vs baseline: 1.1384x; 1.0014x over previous
//
#include <hip/hip_runtime.h>
#include <hip/hip_bf16.h>

#define H 512
#define B 64
#define S 2048

typedef __bf16 bf16x8 __attribute__((ext_vector_type(8)));
typedef float f32x4 __attribute__((ext_vector_type(4)));
typedef unsigned int u32x4 __attribute__((ext_vector_type(4)));

// pack two fp32 -> two bf16 (RNE) in one uint (low = x)
__device__ __forceinline__ unsigned cvt2(float x, float y) {
    union { __hip_bfloat162 h; unsigned u; } cv;
    cv.h = __float22bfloat162_rn(make_float2(x, y));
    return cv.u;
}

__device__ __forceinline__ float fast_tanh(float x) {
    float e = __expf(2.0f * x);
    float r = __builtin_amdgcn_rcpf(e + 1.0f);
    return 1.0f - 2.0f * r;
}

// async 16B global -> LDS (wave-uniform LDS base + lane*16; global addr per-lane)
__device__ __forceinline__ void gload_lds16(const void* g, void* l) {
    __builtin_amdgcn_global_load_lds(
        (const __attribute__((address_space(1))) unsigned int*)g,
        (__attribute__((address_space(3))) unsigned int*)l, 16, 0, 0);
}

// W_w fp32 -> bf16 once (removes the per-K-step repack from the hot loop)
__global__ __launch_bounds__(256) void w16_kernel(const float* __restrict__ Ww,
                                                  unsigned short* __restrict__ w16) {
    const int i = (blockIdx.x * 256 + threadIdx.x) * 8;
    float4 a = *(const float4*)(Ww + i);
    float4 b = *(const float4*)(Ww + i + 4);
    uint4 p;
    p.x = cvt2(a.x, a.y); p.y = cvt2(a.z, a.w);
    p.z = cvt2(b.x, b.y); p.w = cvt2(b.z, b.w);
    *(uint4*)(w16 + i) = p;
}

// u[b,k] = U_b[k] + W_b[k] + sum_h U_w[k,h] * hid[b,h]
__global__ __launch_bounds__(256) void u_kernel(
        const float* __restrict__ hid, const float* __restrict__ Uw,
        const float* __restrict__ Ub, const float* __restrict__ Wb,
        float* __restrict__ u) {
    const int b = blockIdx.y;
    const int k = blockIdx.x * 4 + (threadIdx.x >> 6);
    const int lane = threadIdx.x & 63;
    const float4* wrow = (const float4*)(Uw + (size_t)k * H);
    const float4* hrow = (const float4*)(hid + (size_t)b * H);
    float4 w0 = wrow[lane * 2], w1 = wrow[lane * 2 + 1];
    float4 h0 = hrow[lane * 2], h1 = hrow[lane * 2 + 1];
    float acc = w0.x * h0.x + w0.y * h0.y + w0.z * h0.z + w0.w * h0.w
              + w1.x * h1.x + w1.y * h1.y + w1.z * h1.z + w1.w * h1.w;
    #pragma unroll
    for (int off = 1; off < 64; off <<= 1) acc += __shfl_xor(acc, off, 64);
    if (lane == 0) u[b * H + k] = acc + Ub[k] + Wb[k];
}

// ---------------------------------------------------------------------------
// energy: enc -> A-fragment REGISTERS once (32 rows/wave x full H, bf16),
// pinned resident via empty-asm "+v" keep-alive (prevents the compiler from
// re-materializing the global loads inside the chunk loop — that re-load was
// 4 GB of L2 traffic and the round-1 bottleneck).
// W16 streamed through double-buffered LDS chunks via global_load_lds with
// counted vmcnt(8); XOR-swizzle on pre-swizzled global source + ds_read addr.
// ---------------------------------------------------------------------------
#define CN  32
#define NCH 16               // H / CN
#define CHB (CN * H * 2)     // 32768 bytes per chunk

__global__ __launch_bounds__(256, 2) void energy_kernel(
        const float* __restrict__ enc, const unsigned short* __restrict__ w16,
        const float* __restrict__ Vw, const float* __restrict__ u,
        float* __restrict__ energy) {
    const int s0  = blockIdx.x * 128;
    const int b   = blockIdx.y;
    const int tid = threadIdx.x;
    const int wave = tid >> 6, lane = tid & 63;
    const int quad = lane >> 4, c = lane & 15;

    __shared__ unsigned char Bs[2][CHB];      // 64 KB double buffer
    __shared__ float uS[H], vS[H];            // 4 KB

    // stage W chunk 0 (issued first -> oldest in vmcnt FIFO)
    #pragma unroll
    for (int i = 0; i < 8; ++i) {
        const int row = i * 4 + wave;                 // wave-uniform LDS row
        const int d   = (row << 10) + lane * 16;
        gload_lds16((const unsigned char*)w16 + (d ^ ((row & 7) << 4)),
                    &Bs[0][row << 10]);
    }

    for (int i = tid; i < H; i += 256) { uS[i] = u[b * H + i]; vS[i] = Vw[i]; }

    // A panel -> registers: lane holds rows (g*16 + c), h = t*32 + quad*8 .. +7
    // batched 8 rows at a time to cap transient register pressure
    u32x4 apack[2][16];
    #pragma unroll
    for (int g = 0; g < 2; ++g) {
        const float* pa = enc + ((size_t)(b * S + s0 + wave * 32 + g * 16 + c)) * H + quad * 8;
        #pragma unroll
        for (int half = 0; half < 2; ++half) {
            float4 x0[8], x1[8];
            #pragma unroll
            for (int q = 0; q < 8; ++q) {
                const int t = half * 8 + q;
                x0[q] = *(const float4*)(pa + t * 32);
                x1[q] = *(const float4*)(pa + t * 32 + 4);
            }
            #pragma unroll
            for (int q = 0; q < 8; ++q) {
                u32x4 p;
                p[0] = cvt2(x0[q].x, x0[q].y); p[1] = cvt2(x0[q].z, x0[q].w);
                p[2] = cvt2(x1[q].x, x1[q].y); p[3] = cvt2(x1[q].z, x1[q].w);
                apack[g][half * 8 + q] = p;
            }
        }
    }
    // pin the converted panel in VGPRs: opaque to the optimizer, so the
    // global loads above CANNOT be sunk/re-materialized into the chunk loop.
    #pragma unroll
    for (int g = 0; g < 2; ++g)
        #pragma unroll
        for (int t = 0; t < 16; ++t)
            asm volatile("" : "+v"(apack[g][t]));

    float esum[2][4] = {};
    const int mask = (c & 7) << 4;

    #pragma unroll 2
    for (int cc = 0; cc < NCH; ++cc) {
        const int buf = cc & 1;
        if (cc) __syncthreads();             // all waves done reading buf^1
        if (cc < NCH - 1) {                  // prefetch chunk cc+1
            const unsigned char* src = (const unsigned char*)w16 + (cc + 1) * CHB;
            #pragma unroll
            for (int i = 0; i < 8; ++i) {
                const int row = i * 4 + wave;
                const int d   = (row << 10) + lane * 16;
                gload_lds16(src + (d ^ ((row & 7) << 4)), &Bs[buf ^ 1][row << 10]);
            }
            asm volatile("s_waitcnt vmcnt(8)" ::: "memory");  // chunk cc done, cc+1 in flight
        } else {
            asm volatile("s_waitcnt vmcnt(0)" ::: "memory");
        }
        __syncthreads();

        const unsigned char* bb = Bs[buf];
        f32x4 acc[2][2] = {};
        #pragma unroll
        for (int t = 0; t < 16; ++t) {
            const int base = t * 64 + quad * 16;
            bf16x8 b0 = *(const bf16x8*)(bb + ((( c       << 10) + base) ^ mask));
            bf16x8 b1 = *(const bf16x8*)(bb + ((((16 + c) << 10) + base) ^ mask));
            acc[0][0] = __builtin_amdgcn_mfma_f32_16x16x32_bf16(*(const bf16x8*)&apack[0][t], b0, acc[0][0], 0, 0, 0);
            acc[1][0] = __builtin_amdgcn_mfma_f32_16x16x32_bf16(*(const bf16x8*)&apack[1][t], b0, acc[1][0], 0, 0, 0);
            acc[0][1] = __builtin_amdgcn_mfma_f32_16x16x32_bf16(*(const bf16x8*)&apack[0][t], b1, acc[0][1], 0, 0, 0);
            acc[1][1] = __builtin_amdgcn_mfma_f32_16x16x32_bf16(*(const bf16x8*)&apack[1][t], b1, acc[1][1], 0, 0, 0);
        }
        // fold chunk into energies: esum[g][r] += v[col]*tanh(u[col]+C)
        #pragma unroll
        for (int ct = 0; ct < 2; ++ct) {
            const int col = cc * CN + ct * 16 + c;
            const float vv = vS[col], uu = uS[col];
            #pragma unroll
            for (int g = 0; g < 2; ++g)
                #pragma unroll
                for (int r = 0; r < 4; ++r)
                    esum[g][r] += vv * fast_tanh(uu + acc[g][ct][r]);
        }
    }

    // reduce over the 16 col-lanes; each wave owns its rows -> direct store
    #pragma unroll
    for (int g = 0; g < 2; ++g)
        #pragma unroll
        for (int r = 0; r < 4; ++r) {
            float e = esum[g][r];
            e += __shfl_xor(e, 1, 64);
            e += __shfl_xor(e, 2, 64);
            e += __shfl_xor(e, 4, 64);
            e += __shfl_xor(e, 8, 64);
            if (c == 0)
                energy[b * S + s0 + wave * 32 + g * 16 + quad * 4 + r] = e;
        }
}

__global__ void softmax_kernel(const float* __restrict__ energy, float* __restrict__ attn) {
    int b = blockIdx.x;
    int t = threadIdx.x;              // 256
    const float* e = energy + b * S;
    float v[8];
    float m = -1e30f;
    #pragma unroll
    for (int i = 0; i < 8; ++i) { v[i] = e[t + i * 256]; m = fmaxf(m, v[i]); }
    #pragma unroll
    for (int off = 1; off < 64; off <<= 1) m = fmaxf(m, __shfl_xor(m, off, 64));
    __shared__ float redm[4], reds[4];
    if ((t & 63) == 0) redm[t >> 6] = m;
    __syncthreads();
    m = fmaxf(fmaxf(redm[0], redm[1]), fmaxf(redm[2], redm[3]));
    float s = 0.f;
    #pragma unroll
    for (int i = 0; i < 8; ++i) { v[i] = __expf(v[i] - m); s += v[i]; }
    #pragma unroll
    for (int off = 1; off < 64; off <<= 1) s += __shfl_xor(s, off, 64);
    if ((t & 63) == 0) reds[t >> 6] = s;
    __syncthreads();
    float inv = 1.0f / (reds[0] + reds[1] + reds[2] + reds[3]);
    #pragma unroll
    for (int i = 0; i < 8; ++i) attn[b * S + t + i * 256] = v[i] * inv;
}

// context: float4 loads (16B/lane), 2 s-groups x 128 h-lanes, LDS combine,
// then one atomicAdd set per block (16 blocks per b).
#define CCH 128
__global__ __launch_bounds__(256) void context_kernel(
        const float* __restrict__ enc, const float* __restrict__ attn,
        float* __restrict__ ctx) {
    const int b  = blockIdx.x >> 4;
    const int ch = blockIdx.x & 15;
    const int t  = threadIdx.x;          // 256
    const int grp = t >> 7;              // 0/1: s-half
    const int ln  = t & 127;             // h-lane (float4)
    __shared__ float aS[CCH];
    __shared__ float red[H];
    if (t < CCH) aS[t] = attn[b * S + ch * CCH + t];
    __syncthreads();
    const float* ebase = enc + ((size_t)(b * S + ch * CCH) + grp * 64) * H + ln * 4;
    float4 acc = make_float4(0.f, 0.f, 0.f, 0.f);
    #pragma unroll 8
    for (int s = 0; s < 64; ++s) {
        const float a = aS[grp * 64 + s];
        const float4 e = *(const float4*)(ebase + (size_t)s * H);
        acc.x += a * e.x; acc.y += a * e.y; acc.z += a * e.z; acc.w += a * e.w;
    }
    if (grp == 0) *(float4*)&red[ln * 4] = acc;
    __syncthreads();
    if (grp == 1) {
        const float4 r = *(const float4*)&red[ln * 4];
        atomicAdd(&ctx[b * H + ln * 4 + 0], acc.x + r.x);
        atomicAdd(&ctx[b * H + ln * 4 + 1], acc.y + r.y);
        atomicAdd(&ctx[b * H + ln * 4 + 2], acc.z + r.z);
        atomicAdd(&ctx[b * H + ln * 4 + 3], acc.w + r.w);
    }
}

extern "C" void kernel_launch(void* const* d_in, const int* in_sizes, int n_in,
                              void* d_out, int out_size, void* d_ws, size_t ws_size,
                              hipStream_t stream) {
    (void)in_sizes; (void)n_in; (void)out_size; (void)ws_size;
    const float* hid = (const float*)d_in[0];
    const float* enc = (const float*)d_in[1];
    const float* Uw  = (const float*)d_in[2];
    const float* Ub  = (const float*)d_in[3];
    const float* Ww  = (const float*)d_in[4];
    const float* Wb  = (const float*)d_in[5];
    const float* Vw  = (const float*)d_in[6];
    // V_b unused: softmax shift-invariant, energy not an output.

    float* out_ctx  = (float*)d_out;          // 64*512
    float* out_attn = out_ctx + B * H;        // 64*2048
    float* energy   = (float*)d_ws;           // 64*2048 fp32
    float* u        = energy + B * S;         // 64*512 fp32
    unsigned short* w16 = (unsigned short*)(u + B * H);   // 512*512 bf16

    hipMemsetAsync(d_out, 0, (size_t)B * H * sizeof(float), stream);   // ctx accum target

    w16_kernel<<<dim3(H * H / (256 * 8)), 256, 0, stream>>>(Ww, w16);
    u_kernel<<<dim3(H / 4, B), 256, 0, stream>>>(hid, Uw, Ub, Wb, u);
    energy_kernel<<<dim3(S / 128, B), 256, 0, stream>>>(enc, w16, Vw, u, energy);
    softmax_kernel<<<B, 256, 0, stream>>>(energy, out_attn);
    context_kernel<<<B * 16, 256, 0, stream>>>(enc, out_attn, out_ctx);
}